// Round 16
// baseline (624.487 us; speedup 1.0000x reference)
//
#include <hip/hip_runtime.h>

// Problem constants (B=2, S=2048, HID=2048, H=16, D=128)
#define S_LEN   2048
#define HEADS   16
#define HID_DIM 2048
#define HEAD_D  128
#define BATCH   2

typedef __bf16          bf16x8 __attribute__((ext_vector_type(8)));
typedef unsigned short  u16x8  __attribute__((ext_vector_type(8)));
typedef unsigned short  u16x4  __attribute__((ext_vector_type(4)));
typedef float           f32x4  __attribute__((ext_vector_type(4)));

__device__ __forceinline__ unsigned short f2bf(float f) {
  unsigned u = __builtin_bit_cast(unsigned, f);
  u += 0x7FFFu + ((u >> 16) & 1u);          // round-to-nearest-even
  return (unsigned short)(u >> 16);
}
__device__ __forceinline__ float bf2f(unsigned short s) {
  unsigned u = ((unsigned)s) << 16;
  return __builtin_bit_cast(float, u);
}

__device__ __forceinline__ f32x4 mfma16(u16x8 a, u16x8 b, f32x4 c) {
  return __builtin_amdgcn_mfma_f32_16x16x32_bf16(
      __builtin_bit_cast(bf16x8, a), __builtin_bit_cast(bf16x8, b), c, 0, 0, 0);
}

__device__ __forceinline__ void async_load16(const void* g, void* l) {
  __builtin_amdgcn_global_load_lds(
      (const __attribute__((address_space(1))) void*)g,
      (__attribute__((address_space(3))) void*)l, 16, 0, 0);
}

// ---------------- f32 -> bf16 convert (vectorized) ----------------
__global__ __launch_bounds__(256) void cvt_bf16(const float* __restrict__ in,
                                                unsigned short* __restrict__ out,
                                                int n8) {
  for (int i = blockIdx.x * blockDim.x + threadIdx.x; i < n8;
       i += gridDim.x * blockDim.x) {
    const float4* p = (const float4*)in + 2L * i;
    float4 a = p[0], b = p[1];
    u16x8 v;
    v[0] = f2bf(a.x); v[1] = f2bf(a.y); v[2] = f2bf(a.z); v[3] = f2bf(a.w);
    v[4] = f2bf(b.x); v[5] = f2bf(b.y); v[6] = f2bf(b.z); v[7] = f2bf(b.w);
    ((u16x8*)out)[i] = v;
  }
}

// ---- W (K x N f32) -> Wt (N x K bf16) transpose; z picks one of 3 ----
__global__ __launch_bounds__(256) void transpose_cvt3(
    const float* __restrict__ W0, const float* __restrict__ W1,
    const float* __restrict__ W2, unsigned short* __restrict__ O0,
    unsigned short* __restrict__ O1, unsigned short* __restrict__ O2,
    int dim) {
  __shared__ float tile[32][33];
  const int z = blockIdx.z;
  const float* W = (z == 0) ? W0 : (z == 1) ? W1 : W2;
  unsigned short* Wt = (z == 0) ? O0 : (z == 1) ? O1 : O2;
  const int bx = blockIdx.x * 32, by = blockIdx.y * 32;
  const int tx = threadIdx.x, ty = threadIdx.y;   // 32 x 8
#pragma unroll
  for (int i = 0; i < 32; i += 8)
    tile[ty + i][tx] = W[(long)(by + ty + i) * dim + bx + tx];
  __syncthreads();
#pragma unroll
  for (int i = 0; i < 32; i += 8)
    Wt[(long)(bx + ty + i) * dim + by + tx] = f2bf(tile[tx][ty + i]);
}

__global__ __launch_bounds__(256) void transpose_cvt(const float* __restrict__ W,
                                                     unsigned short* __restrict__ Wt,
                                                     int dim) {
  __shared__ float tile[32][33];
  const int bx = blockIdx.x * 32, by = blockIdx.y * 32;
  const int tx = threadIdx.x, ty = threadIdx.y;   // 32 x 8
#pragma unroll
  for (int i = 0; i < 32; i += 8)
    tile[ty + i][tx] = W[(long)(by + ty + i) * dim + bx + tx];
  __syncthreads();
#pragma unroll
  for (int i = 0; i < 32; i += 8)
    Wt[(long)(bx + ty + i) * dim + by + tx] = f2bf(tile[tx][ty + i]);
}

// ---- V (B*S x HID bf16) -> Vt (bh x D x S bf16) head-transpose ----
__global__ __launch_bounds__(256) void transpose_v(const unsigned short* __restrict__ V,
                                                   unsigned short* __restrict__ Vt) {
  __shared__ unsigned short tile[32][34];
  const int s0 = blockIdx.x * 32, d0 = blockIdx.y * 32, bh = blockIdx.z;
  const int b = bh >> 4, h = bh & 15;
  const int tx = threadIdx.x, ty = threadIdx.y;   // 32 x 8
#pragma unroll
  for (int i = 0; i < 32; i += 8)
    tile[ty + i][tx] =
        V[(long)(b * S_LEN + s0 + ty + i) * HID_DIM + h * HEAD_D + d0 + tx];
  __syncthreads();
#pragma unroll
  for (int i = 0; i < 32; i += 8)
    Vt[((long)bh * HEAD_D + d0 + ty + i) * S_LEN + s0 + tx] = tile[tx][ty + i];
}

// ---- RoPE on Q and K (in-place, bf16); Q also folds in 1/sqrt(D) ----
__global__ __launch_bounds__(256) void rope_qk(unsigned short* __restrict__ Qb,
                                               unsigned short* __restrict__ Kb,
                                               const float* __restrict__ fcos,
                                               const float* __restrict__ fsin) {
  const float SC = 0.08838834764831845f;    // 1/sqrt(128), folded into Q
  const long i = (long)blockIdx.x * blockDim.x + threadIdx.x; // < B*S*H*64
  const int d = (int)(i & 63);
  const int h = (int)((i >> 6) & (HEADS - 1));
  const long row = i >> 10;                 // b*S + s
  const int s = (int)(row & (S_LEN - 1));
  const long base = row * HID_DIM + h * HEAD_D + d;
  const float c0 = fcos[s * HEAD_D + d], c1 = fcos[s * HEAD_D + d + 64];
  const float s0 = fsin[s * HEAD_D + d], s1 = fsin[s * HEAD_D + d + 64];
  const float q0 = bf2f(Qb[base]), q1 = bf2f(Qb[base + 64]);
  Qb[base]      = f2bf((q0 * c0 - q1 * s0) * SC);
  Qb[base + 64] = f2bf((q1 * c1 + q0 * s1) * SC);
  const float k0 = bf2f(Kb[base]), k1 = bf2f(Kb[base + 64]);
  Kb[base]      = f2bf(k0 * c0 - k1 * s0);
  Kb[base + 64] = f2bf(k1 * c1 + k0 * s1);
}

// ---- GEMM v10 (QKV): BM=256 x BN=128, wave tile 128x64 (MF=8) ----
// 2-slot ring (48KB -> 3 blocks/CU): round-13's wave-tile geometry
// (375 B LDS-read/MFMA) + round-9's co-residency.  Stage-1-ahead,
// drain vmcnt at K-tile boundary (cross-block TLP hides the stall),
// ONE barrier per K-tile, setprio, T2 swizzle.
__global__ __launch_bounds__(256, 3) void gemm13(
    const unsigned short* __restrict__ A,
    const unsigned short* __restrict__ Bt0,
    unsigned short* __restrict__ Cb0,
    int M, int N, int K, long zsB, long zsC) {
  __shared__ __align__(16) unsigned short Abuf[2][256 * 32];  // 32KB
  __shared__ __align__(16) unsigned short Bbuf[2][128 * 32];  // 16KB
  const int t = threadIdx.x;         // 256
  const int lane = t & 63;
  const int w = t >> 6;              // 4 waves, 2M x 2N
  const int wr = w >> 1, wc = w & 1;
  const int l15 = lane & 15, l4 = lane >> 4;

  // XCD-chunked bijective swizzle (gridDim.x % 8 == 0)
  const int nwg = gridDim.x;
  const int bid = blockIdx.x;
  const int sw = (bid & 7) * (nwg >> 3) + (bid >> 3);
  const int nbx = N >> 7, nby = M >> 8;
  const int z = sw / (nbx * nby);
  const int rem = sw - z * nbx * nby;
  const int by = rem / nbx;
  const int bx = rem - by * nbx;

  const unsigned short* Bt = Bt0 + (long)z * zsB;
  unsigned short* Cb = Cb0 + (long)z * zsC;

  f32x4 acc[8][4] = {};

  // staging: 4 threads per 64B (32-elem) row; pre-swizzled source col
  const int kcol = 8 * ((t & 3) ^ ((t >> 3) & 3));
  const unsigned short* aSrc = A + ((long)by * 256 + (t >> 2)) * K + kcol;
  const unsigned short* bSrc = Bt + ((long)bx * 128 + (t >> 2)) * K + kcol;

  // swizzled fragment read offsets (validated conflict-free, r5: cnt=0)
  const int swzr = 8 * (l4 ^ ((l15 >> 1) & 3));
  const int aROff = (wr * 128 + l15) * 32 + swzr;   // + mi*512
  const int bROff = (wc * 64 + l15) * 32 + swzr;    // + ni*512

  const int NT = K >> 5;             // 32-wide K-tiles

#define STG(slot, kt_) do {                                              \
    _Pragma("unroll")                                                    \
    for (int r_ = 0; r_ < 4; ++r_)                                       \
      async_load16(aSrc + (long)(kt_) * 32 + (long)r_ * 64 * K,          \
                   (char*)(&Abuf[slot][0]) + r_ * 4096 + t * 16);        \
    _Pragma("unroll")                                                    \
    for (int r_ = 0; r_ < 2; ++r_)                                       \
      async_load16(bSrc + (long)(kt_) * 32 + (long)r_ * 64 * K,          \
                   (char*)(&Bbuf[slot][0]) + r_ * 4096 + t * 16);        \
  } while (0)

  // prologue: stage tile 0, drain, barrier
  STG(0, 0);
  asm volatile("s_waitcnt vmcnt(0)" ::: "memory");
  __builtin_amdgcn_s_barrier();

  for (int kt = 0; kt < NT; ++kt) {
    const int slot = kt & 1;
    const unsigned short* Ab = &Abuf[slot][0];
    const unsigned short* Bb = &Bbuf[slot][0];
    u16x8 af[8], bfr[4];
#pragma unroll
    for (int n = 0; n < 4; ++n) bfr[n] = *(const u16x8*)&Bb[bROff + n * 512];
#pragma unroll
    for (int m = 0; m < 8; ++m) af[m] = *(const u16x8*)&Ab[aROff + m * 512];
    if (kt + 1 < NT) STG(slot ^ 1, kt + 1);  // other slot: reads done iter kt-1
    __builtin_amdgcn_s_setprio(1);
#pragma unroll
    for (int m = 0; m < 8; ++m)
#pragma unroll
      for (int n = 0; n < 4; ++n)
        acc[m][n] = mfma16(af[m], bfr[n], acc[m][n]);
    __builtin_amdgcn_s_setprio(0);
    __builtin_amdgcn_sched_barrier(0);
    if (kt + 1 < NT) {
      asm volatile("s_waitcnt vmcnt(0)" ::: "memory");  // tile kt+1 landed
      __builtin_amdgcn_s_barrier();
    }
  }
#undef STG

  // ---- epilogue ----
  const long orow = (long)by * 256 + wr * 128 + l4 * 4;
  const long ocol = (long)bx * 128 + wc * 64 + l15;
#pragma unroll
  for (int m = 0; m < 8; ++m)
#pragma unroll
    for (int n = 0; n < 4; ++n)
#pragma unroll
      for (int r = 0; r < 4; ++r)
        Cb[(orow + m * 16 + r) * N + ocol + n * 16] = f2bf(acc[m][n][r]);
}

// ---- GEMM v6 (Wo): BM=BN=128, 4 waves 64x64, 3 blocks/CU ----
__global__ __launch_bounds__(256, 3) void gemm10(
    const unsigned short* __restrict__ A,
    const unsigned short* __restrict__ Bt0,
    unsigned short* __restrict__ Cb0,
    float* __restrict__ Cf,
    int M, int N, int K, long zsB, long zsC) {
  __shared__ __align__(16) unsigned short Abuf[3][128 * 32];
  __shared__ __align__(16) unsigned short Bbuf[3][128 * 32];
  const int t = threadIdx.x;         // 256
  const int lane = t & 63;
  const int w = t >> 6;              // 4 waves, 2M x 2N
  const int wr = w >> 1, wc = w & 1;
  const int l15 = lane & 15, l4 = lane >> 4;

  const int nwg = gridDim.x;
  const int bid = blockIdx.x;
  const int sw = (bid & 7) * (nwg >> 3) + (bid >> 3);
  const int nbx = N >> 7, nby = M >> 7;
  const int z = sw / (nbx * nby);
  const int rem = sw - z * nbx * nby;
  const int by = rem / nbx;
  const int bx = rem - by * nbx;

  const unsigned short* Bt = Bt0 + (long)z * zsB;
  unsigned short* Cb = Cb0 ? Cb0 + (long)z * zsC : nullptr;

  f32x4 acc[4][4] = {};

  const int kcol = 8 * ((t & 3) ^ ((t >> 3) & 3));
  const unsigned short* aSrc = A + ((long)by * 128 + (t >> 2)) * K + kcol;
  const unsigned short* bSrc = Bt + ((long)bx * 128 + (t >> 2)) * K + kcol;

  const int swzr = 8 * (l4 ^ ((l15 >> 1) & 3));
  const int aROff = (wr * 64 + l15) * 32 + swzr;
  const int bROff = (wc * 64 + l15) * 32 + swzr;

  const int NT = K >> 5;             // 32-wide K-tiles

#define STG(slot, kt_) do {                                              \
    async_load16(aSrc + (long)(kt_) * 32,                                \
                 (char*)(&Abuf[slot][0]) + t * 16);                      \
    async_load16(aSrc + (long)(kt_) * 32 + 64L * K,                      \
                 (char*)(&Abuf[slot][0]) + 4096 + t * 16);               \
    async_load16(bSrc + (long)(kt_) * 32,                                \
                 (char*)(&Bbuf[slot][0]) + t * 16);                      \
    async_load16(bSrc + (long)(kt_) * 32 + 64L * K,                      \
                 (char*)(&Bbuf[slot][0]) + 4096 + t * 16);               \
  } while (0)

  STG(0, 0);
  STG(1, 1);
  asm volatile("s_waitcnt vmcnt(4)" ::: "memory");
  __builtin_amdgcn_s_barrier();

  int cur = 0;
  for (int kt = 0; kt < NT; ++kt) {
    const unsigned short* Ab = &Abuf[cur][0];
    const unsigned short* Bb = &Bbuf[cur][0];
    const bool stg = (kt + 2) < NT;
    u16x8 af[4], bfr[4];
#pragma unroll
    for (int n = 0; n < 4; ++n) bfr[n] = *(const u16x8*)&Bb[bROff + n * 512];
#pragma unroll
    for (int m = 0; m < 4; ++m) af[m] = *(const u16x8*)&Ab[aROff + m * 512];
    if (stg) {
      const int s2 = (cur + 2 >= 3) ? cur - 1 : cur + 2;
      STG(s2, kt + 2);
    }
    __builtin_amdgcn_s_setprio(1);
#pragma unroll
    for (int m = 0; m < 4; ++m)
#pragma unroll
      for (int n = 0; n < 4; ++n)
        acc[m][n] = mfma16(af[m], bfr[n], acc[m][n]);
    __builtin_amdgcn_s_setprio(0);
    __builtin_amdgcn_sched_barrier(0);
    if (kt + 1 < NT) {
      if (stg) asm volatile("s_waitcnt vmcnt(4)" ::: "memory");
      else     asm volatile("s_waitcnt vmcnt(0)" ::: "memory");
      __builtin_amdgcn_s_barrier();
    }
    cur = (cur + 1 >= 3) ? 0 : cur + 1;
  }
#undef STG

  const long orow = (long)by * 128 + wr * 64 + l4 * 4;
  const long ocol = (long)bx * 128 + wc * 64 + l15;
#pragma unroll
  for (int m = 0; m < 4; ++m)
#pragma unroll
    for (int n = 0; n < 4; ++n)
#pragma unroll
      for (int r = 0; r < 4; ++r) {
        const long row = orow + m * 16 + r;
        const long col = ocol + n * 16;
        if (Cb) Cb[row * N + col] = f2bf(acc[m][n][r]);
        else    Cf[row * N + col] = acc[m][n][r];
      }
}

// --------------- fused causal+alibi flash attention v9 -------------
// (round-11 champion, VGPR <= 128 verified)
__global__ __launch_bounds__(256, 4) void attn_fwd9(
    const unsigned short* __restrict__ Q,
    const unsigned short* __restrict__ K,
    const unsigned short* __restrict__ Vt,
    const float* __restrict__ alibi,
    unsigned short* __restrict__ O) {
  __shared__ __align__(16) unsigned short Kl[2][32 * 128];  // [k][d] swz
  __shared__ __align__(16) unsigned short Vl[2][64 * 64];   // [d>>1][(d&1),k] swz
  __shared__ __align__(16) unsigned short Pl[4][32][40];    // per-wave P
  const int t = threadIdx.x;
  const int lane = t & 63;
  const int w = t >> 6;
  const int l15 = lane & 15, l4 = lane >> 4;

  const int bid = blockIdx.x;                 // 512 blocks
  const int xcd = bid & 7;
  const int idx = bid >> 3;                   // 0..63
  const int qh = idx >> 4;                    // 0..3  (bh within xcd)
  const int ql = idx & 15;
  const int qt = (qh < 2) ? ql : (15 - ql);   // per-CU pairs sum to 15
  const int bh = xcd * 4 + qh;
  const int b = bh >> 4, h = bh & 15;
  const int q0b = qt * 128;
  const int q0 = q0b + w * 32;                 // wave's first q row
  const float nslope = alibi[h * S_LEN + 1];   // = -slope_h

  const long rowbase = ((long)b * S_LEN) * HID_DIM + h * HEAD_D; // Q,K,O
  const long vtbase  = ((long)bh * HEAD_D) * S_LEN;              // Vt

  u16x8 qf[2][4];
  {
    const unsigned short* qp = Q + rowbase + (long)(q0 + l15) * HID_DIM + l4 * 8;
#pragma unroll
    for (int m = 0; m < 2; ++m)
#pragma unroll
      for (int ds = 0; ds < 4; ++ds)
        qf[m][ds] = *(const u16x8*)(qp + (long)m * 16 * HID_DIM + ds * 32);
  }

  f32x4 acc[2][8] = {};
  float m_r[2] = {-1e30f, -1e30f};
  float l_r[2] = {0.f, 0.f};

  int dd, rw, cbl;
  dd = 16 * t;        rw = dd >> 8; cbl = (dd & 255) ^ ((rw & 7) << 4);
  const unsigned short* ksrc0 = K + rowbase + (long)rw * HID_DIM + (cbl >> 1);
  dd = 4096 + 16 * t; rw = dd >> 8; cbl = (dd & 255) ^ ((rw & 7) << 4);
  const unsigned short* ksrc1 = K + rowbase + (long)rw * HID_DIM + (cbl >> 1);
  dd = 16 * t;        rw = dd >> 7; cbl = (dd & 127) ^ ((rw & 3) << 4);
  const unsigned short* vsrc0 =
      Vt + vtbase + (long)(2 * rw + (cbl >> 6)) * S_LEN + ((cbl & 63) >> 1);
  dd = 4096 + 16 * t; rw = dd >> 7; cbl = (dd & 127) ^ ((rw & 3) << 4);
  const unsigned short* vsrc1 =
      Vt + vtbase + (long)(2 * rw + (cbl >> 6)) * S_LEN + ((cbl & 63) >> 1);

#define ASTAGE(buf, kt_) do {                                             \
    const long kadd = (long)(kt_) * 32 * HID_DIM;                         \
    async_load16(ksrc0 + kadd, (char*)(&Kl[buf][0]) + 16 * t);            \
    async_load16(ksrc1 + kadd, (char*)(&Kl[buf][0]) + 4096 + 16 * t);     \
    async_load16(vsrc0 + (kt_) * 32, (char*)(&Vl[buf][0]) + 16 * t);      \
    async_load16(vsrc1 + (kt_) * 32, (char*)(&Vl[buf][0]) + 4096 + 16 * t); \
  } while (0)

  const int ntB = qt * 4 + 4;            // block tile count
  const int mykt = q0 >> 5;              // wave's causal last tile

  ASTAGE(0, 0);
  __syncthreads();                       // drain vmcnt, tile 0 ready

  int cur = 0;
  for (int kt = 0; kt < ntB; ++kt) {
    const int kb = kt * 32;
    if (kt + 1 < ntB) ASTAGE(cur ^ 1, kt + 1);   // prefetch next tile
    if (kt <= mykt) {
      const char* Kc = (const char*)&Kl[cur][0];
      const char* Vc = (const char*)&Vl[cur][0];
      f32x4 sacc[2][2] = {};               // [n][m]
#pragma unroll
      for (int ds = 0; ds < 4; ++ds) {
        u16x8 kfr[2];
#pragma unroll
        for (int n = 0; n < 2; ++n) {
          const int R = 16 * n + l15;
          const int cb = (ds * 64 + l4 * 16) ^ ((l15 & 7) << 4);
          kfr[n] = *(const u16x8*)(Kc + R * 256 + cb);
        }
#pragma unroll
        for (int n = 0; n < 2; ++n)
#pragma unroll
          for (int m = 0; m < 2; ++m)
            sacc[n][m] = mfma16(kfr[n], qf[m][ds], sacc[n][m]);
      }
#pragma unroll
      for (int m = 0; m < 2; ++m) {
        const int q = q0 + 16 * m + l15;
        float pv[2][4];
        float rmax = -1e30f;
#pragma unroll
        for (int n = 0; n < 2; ++n)
#pragma unroll
          for (int r = 0; r < 4; ++r) {
            const int k = kb + 16 * n + l4 * 4 + r;
            float v = sacc[n][m][r] + nslope * (float)k;   // scale in Q
            if (k > q) v = -1e30f;
            pv[n][r] = v;
            rmax = fmaxf(rmax, v);
          }
        rmax = fmaxf(rmax, __shfl_xor(rmax, 16, 64));
        rmax = fmaxf(rmax, __shfl_xor(rmax, 32, 64));
        // T13 defer-max: only rescale when the max grew by > 8
        if (__ballot(rmax > m_r[m] + 8.f)) {
          const float mnew = fmaxf(m_r[m], rmax);
          const float sf = __expf(m_r[m] - mnew);
          m_r[m] = mnew;
          l_r[m] *= sf;
          float sfo[4];
#pragma unroll
          for (int r = 0; r < 4; ++r) sfo[r] = __shfl(sf, l4 * 4 + r, 64);
#pragma unroll
          for (int dt = 0; dt < 8; ++dt)
#pragma unroll
            for (int r = 0; r < 4; ++r) acc[m][dt][r] *= sfo[r];
        }
        float rsum = 0.f;
#pragma unroll
        for (int n = 0; n < 2; ++n)
#pragma unroll
          for (int r = 0; r < 4; ++r) {
            pv[n][r] = __expf(pv[n][r] - m_r[m]);   // bounded by e^8
            rsum += pv[n][r];
          }
        rsum += __shfl_xor(rsum, 16, 64);
        rsum += __shfl_xor(rsum, 32, 64);
        l_r[m] += rsum;
#pragma unroll
        for (int n = 0; n < 2; ++n) {
          u16x4 pk;
#pragma unroll
          for (int r = 0; r < 4; ++r) pk[r] = f2bf(pv[n][r]);
          *(u16x4*)&Pl[w][16 * m + l15][16 * n + l4 * 4] = pk;
        }
      }
      u16x8 pf[2];
#pragma unroll
      for (int m = 0; m < 2; ++m)
        pf[m] = *(const u16x8*)&Pl[w][16 * m + l15][l4 * 8];
#pragma unroll
      for (int dt = 0; dt < 8; ++dt) {
        const int d = dt * 16 + l15;
        const int vrow = d >> 1;
        const int cbv = (((d & 1) << 6) | (l4 << 4)) ^ ((vrow & 3) << 4);
        u16x8 vb = *(const u16x8*)(Vc + vrow * 128 + cbv);
#pragma unroll
        for (int m = 0; m < 2; ++m)
          acc[m][dt] = mfma16(pf[m], vb, acc[m][dt]);
      }
    }
    __builtin_amdgcn_sched_barrier(0);
    __syncthreads();                     // buf reads done + next tile landed
    cur ^= 1;
  }
#undef ASTAGE

#pragma unroll
  for (int m = 0; m < 2; ++m) {
    float linv[4];
#pragma unroll
    for (int r = 0; r < 4; ++r)
      linv[r] = 1.0f / __shfl(l_r[m], l4 * 4 + r, 64);
#pragma unroll
    for (int dt = 0; dt < 8; ++dt)
#pragma unroll
      for (int r = 0; r < 4; ++r) {
        const long row = q0 + 16 * m + l4 * 4 + r;
        O[rowbase + row * HID_DIM + dt * 16 + l15] = f2bf(acc[m][dt][r] * linv[r]);
      }
  }
}

extern "C" void kernel_launch(void* const* d_in, const int* in_sizes, int n_in,
                              void* d_out, int out_size, void* d_ws, size_t ws_size,
                              hipStream_t stream) {
  const float* x    = (const float*)d_in[0];
  const float* Wq   = (const float*)d_in[1];
  const float* Wk   = (const float*)d_in[2];
  const float* Wv   = (const float*)d_in[3];
  const float* Wo   = (const float*)d_in[4];
  // d_in[5] = attention_mask (causal, reproduced analytically)
  const float* alibi = (const float*)d_in[6];
  const float* fcos  = (const float*)d_in[7];
  const float* fsin  = (const float*)d_in[8];

  char* ws = (char*)d_ws;
  unsigned short* xb  = (unsigned short*)(ws);
  unsigned short* wtq = (unsigned short*)(ws + (16L << 20));
  unsigned short* wtk = (unsigned short*)(ws + (24L << 20));
  unsigned short* wtv = (unsigned short*)(ws + (32L << 20));
  unsigned short* VtG = (unsigned short*)(ws + (24L << 20));
  unsigned short* Qb  = (unsigned short*)(ws + (40L << 20));
  unsigned short* Kb  = (unsigned short*)(ws + (56L << 20));
  unsigned short* Vb  = (unsigned short*)(ws + (72L << 20));

  const int M = BATCH * S_LEN;   // 4096
  const int N = HID_DIM;         // 2048
  const int K = HID_DIM;         // 2048

  cvt_bf16<<<2048, 256, 0, stream>>>(x, xb, M * K / 8);

  dim3 tb(32, 8);
  transpose_cvt3<<<dim3(N / 32, K / 32, 3), tb, 0, stream>>>(
      Wq, Wk, Wv, wtq, wtk, wtv, N);

  // fused QKV: 256x128 tiles, 3 z-panels -> 768 blocks (wave tile 128x64)
  gemm13<<<3 * (M / 256) * (N / 128), 256, 0, stream>>>(
      xb, wtq, Qb, M, N, K,
      (long)HID_DIM * HID_DIM, (long)(8 << 20));

  rope_qk<<<(BATCH * S_LEN * HEADS * 64) / 256, 256, 0, stream>>>(Qb, Kb, fcos, fsin);

  transpose_v<<<dim3(S_LEN / 32, HEAD_D / 32, BATCH * HEADS), tb, 0, stream>>>(Vb, VtG);

  transpose_cvt<<<dim3(N / 32, K / 32), tb, 0, stream>>>(Wo, wtq, N);

  attn_fwd9<<<512, 256, 0, stream>>>(Qb, Kb, VtG, alibi, xb);

  // Wo GEMM: gemm10, 512 blocks, all co-resident
  gemm10<<<(M / 128) * (N / 128), 256, 0, stream>>>(
      xb, wtq, nullptr, (float*)d_out, M, N, K, 0L, 0L);
}

// Round 17
// 296.436 us; speedup vs baseline: 2.1066x; 2.1066x over previous
//
#include <hip/hip_runtime.h>

// Problem constants (B=2, S=2048, HID=2048, H=16, D=128)
#define S_LEN   2048
#define HEADS   16
#define HID_DIM 2048
#define HEAD_D  128
#define BATCH   2

typedef __bf16          bf16x8 __attribute__((ext_vector_type(8)));
typedef unsigned short  u16x8  __attribute__((ext_vector_type(8)));
typedef unsigned short  u16x4  __attribute__((ext_vector_type(4)));
typedef float           f32x4  __attribute__((ext_vector_type(4)));

__device__ __forceinline__ unsigned short f2bf(float f) {
  unsigned u = __builtin_bit_cast(unsigned, f);
  u += 0x7FFFu + ((u >> 16) & 1u);          // round-to-nearest-even
  return (unsigned short)(u >> 16);
}
__device__ __forceinline__ float bf2f(unsigned short s) {
  unsigned u = ((unsigned)s) << 16;
  return __builtin_bit_cast(float, u);
}

__device__ __forceinline__ f32x4 mfma16(u16x8 a, u16x8 b, f32x4 c) {
  return __builtin_amdgcn_mfma_f32_16x16x32_bf16(
      __builtin_bit_cast(bf16x8, a), __builtin_bit_cast(bf16x8, b), c, 0, 0, 0);
}

__device__ __forceinline__ void async_load16(const void* g, void* l) {
  __builtin_amdgcn_global_load_lds(
      (const __attribute__((address_space(1))) void*)g,
      (__attribute__((address_space(3))) void*)l, 16, 0, 0);
}

// ---------------- f32 -> bf16 convert (vectorized) ----------------
__global__ __launch_bounds__(256) void cvt_bf16(const float* __restrict__ in,
                                                unsigned short* __restrict__ out,
                                                int n8) {
  for (int i = blockIdx.x * blockDim.x + threadIdx.x; i < n8;
       i += gridDim.x * blockDim.x) {
    const float4* p = (const float4*)in + 2L * i;
    float4 a = p[0], b = p[1];
    u16x8 v;
    v[0] = f2bf(a.x); v[1] = f2bf(a.y); v[2] = f2bf(a.z); v[3] = f2bf(a.w);
    v[4] = f2bf(b.x); v[5] = f2bf(b.y); v[6] = f2bf(b.z); v[7] = f2bf(b.w);
    ((u16x8*)out)[i] = v;
  }
}

// ---- W (K x N f32) -> Wt (N x K bf16) transpose; z picks one of 3 ----
__global__ __launch_bounds__(256) void transpose_cvt3(
    const float* __restrict__ W0, const float* __restrict__ W1,
    const float* __restrict__ W2, unsigned short* __restrict__ O0,
    unsigned short* __restrict__ O1, unsigned short* __restrict__ O2,
    int dim) {
  __shared__ float tile[32][33];
  const int z = blockIdx.z;
  const float* W = (z == 0) ? W0 : (z == 1) ? W1 : W2;
  unsigned short* Wt = (z == 0) ? O0 : (z == 1) ? O1 : O2;
  const int bx = blockIdx.x * 32, by = blockIdx.y * 32;
  const int tx = threadIdx.x, ty = threadIdx.y;   // 32 x 8
#pragma unroll
  for (int i = 0; i < 32; i += 8)
    tile[ty + i][tx] = W[(long)(by + ty + i) * dim + bx + tx];
  __syncthreads();
#pragma unroll
  for (int i = 0; i < 32; i += 8)
    Wt[(long)(bx + ty + i) * dim + by + tx] = f2bf(tile[tx][ty + i]);
}

__global__ __launch_bounds__(256) void transpose_cvt(const float* __restrict__ W,
                                                     unsigned short* __restrict__ Wt,
                                                     int dim) {
  __shared__ float tile[32][33];
  const int bx = blockIdx.x * 32, by = blockIdx.y * 32;
  const int tx = threadIdx.x, ty = threadIdx.y;   // 32 x 8
#pragma unroll
  for (int i = 0; i < 32; i += 8)
    tile[ty + i][tx] = W[(long)(by + ty + i) * dim + bx + tx];
  __syncthreads();
#pragma unroll
  for (int i = 0; i < 32; i += 8)
    Wt[(long)(bx + ty + i) * dim + by + tx] = f2bf(tile[tx][ty + i]);
}

// ---- V (B*S x HID bf16) -> Vt (bh x D x S bf16) head-transpose ----
__global__ __launch_bounds__(256) void transpose_v(const unsigned short* __restrict__ V,
                                                   unsigned short* __restrict__ Vt) {
  __shared__ unsigned short tile[32][34];
  const int s0 = blockIdx.x * 32, d0 = blockIdx.y * 32, bh = blockIdx.z;
  const int b = bh >> 4, h = bh & 15;
  const int tx = threadIdx.x, ty = threadIdx.y;   // 32 x 8
#pragma unroll
  for (int i = 0; i < 32; i += 8)
    tile[ty + i][tx] =
        V[(long)(b * S_LEN + s0 + ty + i) * HID_DIM + h * HEAD_D + d0 + tx];
  __syncthreads();
#pragma unroll
  for (int i = 0; i < 32; i += 8)
    Vt[((long)bh * HEAD_D + d0 + ty + i) * S_LEN + s0 + tx] = tile[tx][ty + i];
}

// ---- RoPE on Q and K (in-place, bf16); Q also folds in 1/sqrt(D) ----
__global__ __launch_bounds__(256) void rope_qk(unsigned short* __restrict__ Qb,
                                               unsigned short* __restrict__ Kb,
                                               const float* __restrict__ fcos,
                                               const float* __restrict__ fsin) {
  const float SC = 0.08838834764831845f;    // 1/sqrt(128), folded into Q
  const long i = (long)blockIdx.x * blockDim.x + threadIdx.x; // < B*S*H*64
  const int d = (int)(i & 63);
  const int h = (int)((i >> 6) & (HEADS - 1));
  const long row = i >> 10;                 // b*S + s
  const int s = (int)(row & (S_LEN - 1));
  const long base = row * HID_DIM + h * HEAD_D + d;
  const float c0 = fcos[s * HEAD_D + d], c1 = fcos[s * HEAD_D + d + 64];
  const float s0 = fsin[s * HEAD_D + d], s1 = fsin[s * HEAD_D + d + 64];
  const float q0 = bf2f(Qb[base]), q1 = bf2f(Qb[base + 64]);
  Qb[base]      = f2bf((q0 * c0 - q1 * s0) * SC);
  Qb[base + 64] = f2bf((q1 * c1 + q0 * s1) * SC);
  const float k0 = bf2f(Kb[base]), k1 = bf2f(Kb[base + 64]);
  Kb[base]      = f2bf(k0 * c0 - k1 * s0);
  Kb[base + 64] = f2bf(k1 * c1 + k0 * s1);
}

// ---- GEMM v9 (QKV): BM=256 x BN=128, wave tile 128x64 (MF=8) ----
// 3-slot ring, stage-2-ahead, counted vmcnt, 1 barrier/K-tile, setprio,
// T2 swizzle.  375 B LDS-read/MFMA.  72KB ring -> 2 blocks/CU.
// NOTE: (256,2) is REQUIRED — acc[8][4]+frags ~ 170 regs; (256,3) spills
// to scratch (round-16: 1.6GB scratch writes, 4x slowdown).
__global__ __launch_bounds__(256, 2) void gemm12(
    const unsigned short* __restrict__ A,
    const unsigned short* __restrict__ Bt0,
    unsigned short* __restrict__ Cb0,
    int M, int N, int K, long zsB, long zsC) {
  __shared__ __align__(16) unsigned short Abuf[3][256 * 32];  // 48KB
  __shared__ __align__(16) unsigned short Bbuf[3][128 * 32];  // 24KB
  const int t = threadIdx.x;         // 256
  const int lane = t & 63;
  const int w = t >> 6;              // 4 waves, 2M x 2N
  const int wr = w >> 1, wc = w & 1;
  const int l15 = lane & 15, l4 = lane >> 4;

  const int nwg = gridDim.x;
  const int bid = blockIdx.x;
  const int sw = (bid & 7) * (nwg >> 3) + (bid >> 3);
  const int nbx = N >> 7, nby = M >> 8;
  const int z = sw / (nbx * nby);
  const int rem = sw - z * nbx * nby;
  const int by = rem / nbx;
  const int bx = rem - by * nbx;

  const unsigned short* Bt = Bt0 + (long)z * zsB;
  unsigned short* Cb = Cb0 + (long)z * zsC;

  f32x4 acc[8][4] = {};

  const int kcol = 8 * ((t & 3) ^ ((t >> 3) & 3));
  const unsigned short* aSrc = A + ((long)by * 256 + (t >> 2)) * K + kcol;
  const unsigned short* bSrc = Bt + ((long)bx * 128 + (t >> 2)) * K + kcol;

  const int swzr = 8 * (l4 ^ ((l15 >> 1) & 3));
  const int aROff = (wr * 128 + l15) * 32 + swzr;   // + mi*512
  const int bROff = (wc * 64 + l15) * 32 + swzr;    // + ni*512

  const int NT = K >> 5;             // 32-wide K-tiles

#define STG(slot, kt_) do {                                              \
    _Pragma("unroll")                                                    \
    for (int r_ = 0; r_ < 4; ++r_)                                       \
      async_load16(aSrc + (long)(kt_) * 32 + (long)r_ * 64 * K,          \
                   (char*)(&Abuf[slot][0]) + r_ * 4096 + t * 16);        \
    _Pragma("unroll")                                                    \
    for (int r_ = 0; r_ < 2; ++r_)                                       \
      async_load16(bSrc + (long)(kt_) * 32 + (long)r_ * 64 * K,          \
                   (char*)(&Bbuf[slot][0]) + r_ * 4096 + t * 16);        \
  } while (0)

  STG(0, 0);
  STG(1, 1);
  asm volatile("s_waitcnt vmcnt(6)" ::: "memory");
  __builtin_amdgcn_s_barrier();

  int cur = 0;
  for (int kt = 0; kt < NT; ++kt) {
    const unsigned short* Ab = &Abuf[cur][0];
    const unsigned short* Bb = &Bbuf[cur][0];
    const bool stg = (kt + 2) < NT;
    u16x8 af[8], bfr[4];
#pragma unroll
    for (int n = 0; n < 4; ++n) bfr[n] = *(const u16x8*)&Bb[bROff + n * 512];
#pragma unroll
    for (int m = 0; m < 8; ++m) af[m] = *(const u16x8*)&Ab[aROff + m * 512];
    if (stg) {
      const int s2 = (cur + 2 >= 3) ? cur - 1 : cur + 2;
      STG(s2, kt + 2);
    }
    __builtin_amdgcn_s_setprio(1);
#pragma unroll
    for (int m = 0; m < 8; ++m)
#pragma unroll
      for (int n = 0; n < 4; ++n)
        acc[m][n] = mfma16(af[m], bfr[n], acc[m][n]);
    __builtin_amdgcn_s_setprio(0);
    __builtin_amdgcn_sched_barrier(0);
    if (kt + 1 < NT) {
      if (stg) asm volatile("s_waitcnt vmcnt(6)" ::: "memory");
      else     asm volatile("s_waitcnt vmcnt(0)" ::: "memory");
      __builtin_amdgcn_s_barrier();
    }
    cur = (cur + 1 >= 3) ? 0 : cur + 1;
  }
#undef STG

  const long orow = (long)by * 256 + wr * 128 + l4 * 4;
  const long ocol = (long)bx * 128 + wc * 64 + l15;
#pragma unroll
  for (int m = 0; m < 8; ++m)
#pragma unroll
    for (int n = 0; n < 4; ++n)
#pragma unroll
      for (int r = 0; r < 4; ++r)
        Cb[(orow + m * 16 + r) * N + ocol + n * 16] = f2bf(acc[m][n][r]);
}

// ---- GEMM v6 (Wo): BM=BN=128, 4 waves 64x64, 3 blocks/CU ----
__global__ __launch_bounds__(256, 3) void gemm10(
    const unsigned short* __restrict__ A,
    const unsigned short* __restrict__ Bt0,
    unsigned short* __restrict__ Cb0,
    float* __restrict__ Cf,
    int M, int N, int K, long zsB, long zsC) {
  __shared__ __align__(16) unsigned short Abuf[3][128 * 32];
  __shared__ __align__(16) unsigned short Bbuf[3][128 * 32];
  const int t = threadIdx.x;         // 256
  const int lane = t & 63;
  const int w = t >> 6;              // 4 waves, 2M x 2N
  const int wr = w >> 1, wc = w & 1;
  const int l15 = lane & 15, l4 = lane >> 4;

  const int nwg = gridDim.x;
  const int bid = blockIdx.x;
  const int sw = (bid & 7) * (nwg >> 3) + (bid >> 3);
  const int nbx = N >> 7, nby = M >> 7;
  const int z = sw / (nbx * nby);
  const int rem = sw - z * nbx * nby;
  const int by = rem / nbx;
  const int bx = rem - by * nbx;

  const unsigned short* Bt = Bt0 + (long)z * zsB;
  unsigned short* Cb = Cb0 ? Cb0 + (long)z * zsC : nullptr;

  f32x4 acc[4][4] = {};

  const int kcol = 8 * ((t & 3) ^ ((t >> 3) & 3));
  const unsigned short* aSrc = A + ((long)by * 128 + (t >> 2)) * K + kcol;
  const unsigned short* bSrc = Bt + ((long)bx * 128 + (t >> 2)) * K + kcol;

  const int swzr = 8 * (l4 ^ ((l15 >> 1) & 3));
  const int aROff = (wr * 64 + l15) * 32 + swzr;
  const int bROff = (wc * 64 + l15) * 32 + swzr;

  const int NT = K >> 5;             // 32-wide K-tiles

#define STG(slot, kt_) do {                                              \
    async_load16(aSrc + (long)(kt_) * 32,                                \
                 (char*)(&Abuf[slot][0]) + t * 16);                      \
    async_load16(aSrc + (long)(kt_) * 32 + 64L * K,                      \
                 (char*)(&Abuf[slot][0]) + 4096 + t * 16);               \
    async_load16(bSrc + (long)(kt_) * 32,                                \
                 (char*)(&Bbuf[slot][0]) + t * 16);                      \
    async_load16(bSrc + (long)(kt_) * 32 + 64L * K,                      \
                 (char*)(&Bbuf[slot][0]) + 4096 + t * 16);               \
  } while (0)

  STG(0, 0);
  STG(1, 1);
  asm volatile("s_waitcnt vmcnt(4)" ::: "memory");
  __builtin_amdgcn_s_barrier();

  int cur = 0;
  for (int kt = 0; kt < NT; ++kt) {
    const unsigned short* Ab = &Abuf[cur][0];
    const unsigned short* Bb = &Bbuf[cur][0];
    const bool stg = (kt + 2) < NT;
    u16x8 af[4], bfr[4];
#pragma unroll
    for (int n = 0; n < 4; ++n) bfr[n] = *(const u16x8*)&Bb[bROff + n * 512];
#pragma unroll
    for (int m = 0; m < 4; ++m) af[m] = *(const u16x8*)&Ab[aROff + m * 512];
    if (stg) {
      const int s2 = (cur + 2 >= 3) ? cur - 1 : cur + 2;
      STG(s2, kt + 2);
    }
    __builtin_amdgcn_s_setprio(1);
#pragma unroll
    for (int m = 0; m < 4; ++m)
#pragma unroll
      for (int n = 0; n < 4; ++n)
        acc[m][n] = mfma16(af[m], bfr[n], acc[m][n]);
    __builtin_amdgcn_s_setprio(0);
    __builtin_amdgcn_sched_barrier(0);
    if (kt + 1 < NT) {
      if (stg) asm volatile("s_waitcnt vmcnt(4)" ::: "memory");
      else     asm volatile("s_waitcnt vmcnt(0)" ::: "memory");
      __builtin_amdgcn_s_barrier();
    }
    cur = (cur + 1 >= 3) ? 0 : cur + 1;
  }
#undef STG

  const long orow = (long)by * 128 + wr * 64 + l4 * 4;
  const long ocol = (long)bx * 128 + wc * 64 + l15;
#pragma unroll
  for (int m = 0; m < 4; ++m)
#pragma unroll
    for (int n = 0; n < 4; ++n)
#pragma unroll
      for (int r = 0; r < 4; ++r) {
        const long row = orow + m * 16 + r;
        const long col = ocol + n * 16;
        if (Cb) Cb[row * N + col] = f2bf(acc[m][n][r]);
        else    Cf[row * N + col] = acc[m][n][r];
      }
}

// --------------- fused causal+alibi flash attention v9 -------------
// (round-11 champion, VGPR <= 128 verified)
__global__ __launch_bounds__(256, 4) void attn_fwd9(
    const unsigned short* __restrict__ Q,
    const unsigned short* __restrict__ K,
    const unsigned short* __restrict__ Vt,
    const float* __restrict__ alibi,
    unsigned short* __restrict__ O) {
  __shared__ __align__(16) unsigned short Kl[2][32 * 128];  // [k][d] swz
  __shared__ __align__(16) unsigned short Vl[2][64 * 64];   // [d>>1][(d&1),k] swz
  __shared__ __align__(16) unsigned short Pl[4][32][40];    // per-wave P
  const int t = threadIdx.x;
  const int lane = t & 63;
  const int w = t >> 6;
  const int l15 = lane & 15, l4 = lane >> 4;

  const int bid = blockIdx.x;                 // 512 blocks
  const int xcd = bid & 7;
  const int idx = bid >> 3;                   // 0..63
  const int qh = idx >> 4;                    // 0..3  (bh within xcd)
  const int ql = idx & 15;
  const int qt = (qh < 2) ? ql : (15 - ql);   // per-CU pairs sum to 15
  const int bh = xcd * 4 + qh;
  const int b = bh >> 4, h = bh & 15;
  const int q0b = qt * 128;
  const int q0 = q0b + w * 32;                 // wave's first q row
  const float nslope = alibi[h * S_LEN + 1];   // = -slope_h

  const long rowbase = ((long)b * S_LEN) * HID_DIM + h * HEAD_D; // Q,K,O
  const long vtbase  = ((long)bh * HEAD_D) * S_LEN;              // Vt

  u16x8 qf[2][4];
  {
    const unsigned short* qp = Q + rowbase + (long)(q0 + l15) * HID_DIM + l4 * 8;
#pragma unroll
    for (int m = 0; m < 2; ++m)
#pragma unroll
      for (int ds = 0; ds < 4; ++ds)
        qf[m][ds] = *(const u16x8*)(qp + (long)m * 16 * HID_DIM + ds * 32);
  }

  f32x4 acc[2][8] = {};
  float m_r[2] = {-1e30f, -1e30f};
  float l_r[2] = {0.f, 0.f};

  int dd, rw, cbl;
  dd = 16 * t;        rw = dd >> 8; cbl = (dd & 255) ^ ((rw & 7) << 4);
  const unsigned short* ksrc0 = K + rowbase + (long)rw * HID_DIM + (cbl >> 1);
  dd = 4096 + 16 * t; rw = dd >> 8; cbl = (dd & 255) ^ ((rw & 7) << 4);
  const unsigned short* ksrc1 = K + rowbase + (long)rw * HID_DIM + (cbl >> 1);
  dd = 16 * t;        rw = dd >> 7; cbl = (dd & 127) ^ ((rw & 3) << 4);
  const unsigned short* vsrc0 =
      Vt + vtbase + (long)(2 * rw + (cbl >> 6)) * S_LEN + ((cbl & 63) >> 1);
  dd = 4096 + 16 * t; rw = dd >> 7; cbl = (dd & 127) ^ ((rw & 3) << 4);
  const unsigned short* vsrc1 =
      Vt + vtbase + (long)(2 * rw + (cbl >> 6)) * S_LEN + ((cbl & 63) >> 1);

#define ASTAGE(buf, kt_) do {                                             \
    const long kadd = (long)(kt_) * 32 * HID_DIM;                         \
    async_load16(ksrc0 + kadd, (char*)(&Kl[buf][0]) + 16 * t);            \
    async_load16(ksrc1 + kadd, (char*)(&Kl[buf][0]) + 4096 + 16 * t);     \
    async_load16(vsrc0 + (kt_) * 32, (char*)(&Vl[buf][0]) + 16 * t);      \
    async_load16(vsrc1 + (kt_) * 32, (char*)(&Vl[buf][0]) + 4096 + 16 * t); \
  } while (0)

  const int ntB = qt * 4 + 4;            // block tile count
  const int mykt = q0 >> 5;              // wave's causal last tile

  ASTAGE(0, 0);
  __syncthreads();                       // drain vmcnt, tile 0 ready

  int cur = 0;
  for (int kt = 0; kt < ntB; ++kt) {
    const int kb = kt * 32;
    if (kt + 1 < ntB) ASTAGE(cur ^ 1, kt + 1);   // prefetch next tile
    if (kt <= mykt) {
      const char* Kc = (const char*)&Kl[cur][0];
      const char* Vc = (const char*)&Vl[cur][0];
      f32x4 sacc[2][2] = {};               // [n][m]
#pragma unroll
      for (int ds = 0; ds < 4; ++ds) {
        u16x8 kfr[2];
#pragma unroll
        for (int n = 0; n < 2; ++n) {
          const int R = 16 * n + l15;
          const int cb = (ds * 64 + l4 * 16) ^ ((l15 & 7) << 4);
          kfr[n] = *(const u16x8*)(Kc + R * 256 + cb);
        }
#pragma unroll
        for (int n = 0; n < 2; ++n)
#pragma unroll
          for (int m = 0; m < 2; ++m)
            sacc[n][m] = mfma16(kfr[n], qf[m][ds], sacc[n][m]);
      }
#pragma unroll
      for (int m = 0; m < 2; ++m) {
        const int q = q0 + 16 * m + l15;
        float pv[2][4];
        float rmax = -1e30f;
#pragma unroll
        for (int n = 0; n < 2; ++n)
#pragma unroll
          for (int r = 0; r < 4; ++r) {
            const int k = kb + 16 * n + l4 * 4 + r;
            float v = sacc[n][m][r] + nslope * (float)k;   // scale in Q
            if (k > q) v = -1e30f;
            pv[n][r] = v;
            rmax = fmaxf(rmax, v);
          }
        rmax = fmaxf(rmax, __shfl_xor(rmax, 16, 64));
        rmax = fmaxf(rmax, __shfl_xor(rmax, 32, 64));
        // T13 defer-max: only rescale when the max grew by > 8
        if (__ballot(rmax > m_r[m] + 8.f)) {
          const float mnew = fmaxf(m_r[m], rmax);
          const float sf = __expf(m_r[m] - mnew);
          m_r[m] = mnew;
          l_r[m] *= sf;
          float sfo[4];
#pragma unroll
          for (int r = 0; r < 4; ++r) sfo[r] = __shfl(sf, l4 * 4 + r, 64);
#pragma unroll
          for (int dt = 0; dt < 8; ++dt)
#pragma unroll
            for (int r = 0; r < 4; ++r) acc[m][dt][r] *= sfo[r];
        }
        float rsum = 0.f;
#pragma unroll
        for (int n = 0; n < 2; ++n)
#pragma unroll
          for (int r = 0; r < 4; ++r) {
            pv[n][r] = __expf(pv[n][r] - m_r[m]);   // bounded by e^8
            rsum += pv[n][r];
          }
        rsum += __shfl_xor(rsum, 16, 64);
        rsum += __shfl_xor(rsum, 32, 64);
        l_r[m] += rsum;
#pragma unroll
        for (int n = 0; n < 2; ++n) {
          u16x4 pk;
#pragma unroll
          for (int r = 0; r < 4; ++r) pk[r] = f2bf(pv[n][r]);
          *(u16x4*)&Pl[w][16 * m + l15][16 * n + l4 * 4] = pk;
        }
      }
      u16x8 pf[2];
#pragma unroll
      for (int m = 0; m < 2; ++m)
        pf[m] = *(const u16x8*)&Pl[w][16 * m + l15][l4 * 8];
#pragma unroll
      for (int dt = 0; dt < 8; ++dt) {
        const int d = dt * 16 + l15;
        const int vrow = d >> 1;
        const int cbv = (((d & 1) << 6) | (l4 << 4)) ^ ((vrow & 3) << 4);
        u16x8 vb = *(const u16x8*)(Vc + vrow * 128 + cbv);
#pragma unroll
        for (int m = 0; m < 2; ++m)
          acc[m][dt] = mfma16(pf[m], vb, acc[m][dt]);
      }
    }
    __builtin_amdgcn_sched_barrier(0);
    __syncthreads();                     // buf reads done + next tile landed
    cur ^= 1;
  }
#undef ASTAGE

#pragma unroll
  for (int m = 0; m < 2; ++m) {
    float linv[4];
#pragma unroll
    for (int r = 0; r < 4; ++r)
      linv[r] = 1.0f / __shfl(l_r[m], l4 * 4 + r, 64);
#pragma unroll
    for (int dt = 0; dt < 8; ++dt)
#pragma unroll
      for (int r = 0; r < 4; ++r) {
        const long row = q0 + 16 * m + l4 * 4 + r;
        O[rowbase + row * HID_DIM + dt * 16 + l15] = f2bf(acc[m][dt][r] * linv[r]);
      }
  }
}

extern "C" void kernel_launch(void* const* d_in, const int* in_sizes, int n_in,
                              void* d_out, int out_size, void* d_ws, size_t ws_size,
                              hipStream_t stream) {
  const float* x    = (const float*)d_in[0];
  const float* Wq   = (const float*)d_in[1];
  const float* Wk   = (const float*)d_in[2];
  const float* Wv   = (const float*)d_in[3];
  const float* Wo   = (const float*)d_in[4];
  // d_in[5] = attention_mask (causal, reproduced analytically)
  const float* alibi = (const float*)d_in[6];
  const float* fcos  = (const float*)d_in[7];
  const float* fsin  = (const float*)d_in[8];

  char* ws = (char*)d_ws;
  unsigned short* xb  = (unsigned short*)(ws);
  unsigned short* wtq = (unsigned short*)(ws + (16L << 20));
  unsigned short* wtk = (unsigned short*)(ws + (24L << 20));
  unsigned short* wtv = (unsigned short*)(ws + (32L << 20));
  unsigned short* VtG = (unsigned short*)(ws + (24L << 20));
  unsigned short* Qb  = (unsigned short*)(ws + (40L << 20));
  unsigned short* Kb  = (unsigned short*)(ws + (56L << 20));
  unsigned short* Vb  = (unsigned short*)(ws + (72L << 20));

  const int M = BATCH * S_LEN;   // 4096
  const int N = HID_DIM;         // 2048
  const int K = HID_DIM;         // 2048

  cvt_bf16<<<2048, 256, 0, stream>>>(x, xb, M * K / 8);

  dim3 tb(32, 8);
  transpose_cvt3<<<dim3(N / 32, K / 32, 3), tb, 0, stream>>>(
      Wq, Wk, Wv, wtq, wtk, wtv, N);

  // fused QKV: 256x128 tiles, 3 z-panels -> 768 blocks (wave tile 128x64)
  gemm12<<<3 * (M / 256) * (N / 128), 256, 0, stream>>>(
      xb, wtq, Qb, M, N, K,
      (long)HID_DIM * HID_DIM, (long)(8 << 20));

  rope_qk<<<(BATCH * S_LEN * HEADS * 64) / 256, 256, 0, stream>>>(Qb, Kb, fcos, fsin);

  transpose_v<<<dim3(S_LEN / 32, HEAD_D / 32, BATCH * HEADS), tb, 0, stream>>>(Vb, VtG);

  transpose_cvt<<<dim3(N / 32, K / 32), tb, 0, stream>>>(Wo, wtq, N);

  attn_fwd9<<<512, 256, 0, stream>>>(Qb, Kb, VtG, alibi, xb);

  // Wo GEMM: gemm10, 512 blocks, all co-resident
  gemm10<<<(M / 128) * (N / 128), 256, 0, stream>>>(
      xb, wtq, nullptr, (float*)d_out, M, N, K, 0L, 0L);
}

// Round 19
// 290.760 us; speedup vs baseline: 2.1478x; 1.0195x over previous
//
#include <hip/hip_runtime.h>

// Problem constants (B=2, S=2048, HID=2048, H=16, D=128)
#define S_LEN   2048
#define HEADS   16
#define HID_DIM 2048
#define HEAD_D  128
#define BATCH   2

typedef __bf16          bf16x8 __attribute__((ext_vector_type(8)));
typedef unsigned short  u16x8  __attribute__((ext_vector_type(8)));
typedef unsigned short  u16x4  __attribute__((ext_vector_type(4)));
typedef float           f32x4  __attribute__((ext_vector_type(4)));

__device__ __forceinline__ unsigned short f2bf(float f) {
  unsigned u = __builtin_bit_cast(unsigned, f);
  u += 0x7FFFu + ((u >> 16) & 1u);          // round-to-nearest-even
  return (unsigned short)(u >> 16);
}
__device__ __forceinline__ float bf2f(unsigned short s) {
  unsigned u = ((unsigned)s) << 16;
  return __builtin_bit_cast(float, u);
}

__device__ __forceinline__ f32x4 mfma16(u16x8 a, u16x8 b, f32x4 c) {
  return __builtin_amdgcn_mfma_f32_16x16x32_bf16(
      __builtin_bit_cast(bf16x8, a), __builtin_bit_cast(bf16x8, b), c, 0, 0, 0);
}

__device__ __forceinline__ void async_load16(const void* g, void* l) {
  __builtin_amdgcn_global_load_lds(
      (const __attribute__((address_space(1))) void*)g,
      (__attribute__((address_space(3))) void*)l, 16, 0, 0);
}

// ---- fused PREP: x f32->bf16 convert + Wq/Wk/Wv transpose-convert ----
// grid: 12288 transpose blocks (3 x 64 x 64) + 2048 cvt blocks = 14336
__global__ __launch_bounds__(256) void fused_prep(
    const float* __restrict__ x, unsigned short* __restrict__ xb,
    const float* __restrict__ W0, const float* __restrict__ W1,
    const float* __restrict__ W2, unsigned short* __restrict__ O0,
    unsigned short* __restrict__ O1, unsigned short* __restrict__ O2) {
  __shared__ float tile[32][33];
  const int bid = blockIdx.x;
  const int t = threadIdx.x;
  if (bid < 12288) {                       // W transpose-convert part
    const int z = bid >> 12;               // /4096
    const int rem = bid & 4095;
    const float* W = (z == 0) ? W0 : (z == 1) ? W1 : W2;
    unsigned short* Wt = (z == 0) ? O0 : (z == 1) ? O1 : O2;
    const int bx = (rem & 63) * 32, by = (rem >> 6) * 32;
    const int tx = t & 31, ty = t >> 5;    // 32 x 8
#pragma unroll
    for (int i = 0; i < 32; i += 8)
      tile[ty + i][tx] = W[(long)(by + ty + i) * HID_DIM + bx + tx];
    __syncthreads();
#pragma unroll
    for (int i = 0; i < 32; i += 8)
      Wt[(long)(bx + ty + i) * HID_DIM + by + tx] = f2bf(tile[tx][ty + i]);
  } else {                                 // x convert part (grid-stride)
    const int n8 = BATCH * S_LEN * HID_DIM / 8;
    for (int i = (bid - 12288) * 256 + t; i < n8; i += 2048 * 256) {
      const float4* p = (const float4*)x + 2L * i;
      float4 a = p[0], b = p[1];
      u16x8 v;
      v[0] = f2bf(a.x); v[1] = f2bf(a.y); v[2] = f2bf(a.z); v[3] = f2bf(a.w);
      v[4] = f2bf(b.x); v[5] = f2bf(b.y); v[6] = f2bf(b.z); v[7] = f2bf(b.w);
      ((u16x8*)xb)[i] = v;
    }
  }
}

// ---- fused MID: RoPE(Q,K) + V head-transpose + Wo transpose-convert ----
// grid: 16384 rope + 8192 tv + 4096 woT = 28672
__global__ __launch_bounds__(256) void fused_mid(
    unsigned short* __restrict__ Qb, unsigned short* __restrict__ Kb,
    const float* __restrict__ fcos, const float* __restrict__ fsin,
    const unsigned short* __restrict__ V, unsigned short* __restrict__ Vt,
    const float* __restrict__ Wo, unsigned short* __restrict__ WoT) {
  __shared__ float ftile[32][33];
  __shared__ unsigned short htile[32][34];
  const int bid = blockIdx.x;
  const int t = threadIdx.x;
  if (bid < 16384) {                       // RoPE part (B*S*H*64 / 256)
    const float SC = 0.08838834764831845f; // 1/sqrt(128) folded into Q
    const long i = (long)bid * 256 + t;    // < B*S*H*64
    const int d = (int)(i & 63);
    const int h = (int)((i >> 6) & (HEADS - 1));
    const long row = i >> 10;              // b*S + s
    const int s = (int)(row & (S_LEN - 1));
    const long base = row * HID_DIM + h * HEAD_D + d;
    const float c0 = fcos[s * HEAD_D + d], c1 = fcos[s * HEAD_D + d + 64];
    const float s0 = fsin[s * HEAD_D + d], s1 = fsin[s * HEAD_D + d + 64];
    const float q0 = bf2f(Qb[base]), q1 = bf2f(Qb[base + 64]);
    Qb[base]      = f2bf((q0 * c0 - q1 * s0) * SC);
    Qb[base + 64] = f2bf((q1 * c1 + q0 * s1) * SC);
    const float k0 = bf2f(Kb[base]), k1 = bf2f(Kb[base + 64]);
    Kb[base]      = f2bf(k0 * c0 - k1 * s0);
    Kb[base + 64] = f2bf(k1 * c1 + k0 * s1);
  } else if (bid < 24576) {                // V head-transpose part
    const int r = bid - 16384;             // s-tile 64 x d-tile 4 x bh 32
    const int s0 = (r & 63) * 32;
    const int d0 = ((r >> 6) & 3) * 32;
    const int bh = r >> 8;
    const int b = bh >> 4, h = bh & 15;
    const int tx = t & 31, ty = t >> 5;    // 32 x 8
#pragma unroll
    for (int i = 0; i < 32; i += 8)
      htile[ty + i][tx] =
          V[(long)(b * S_LEN + s0 + ty + i) * HID_DIM + h * HEAD_D + d0 + tx];
    __syncthreads();
#pragma unroll
    for (int i = 0; i < 32; i += 8)
      Vt[((long)bh * HEAD_D + d0 + ty + i) * S_LEN + s0 + tx] = htile[tx][ty + i];
  } else {                                 // Wo transpose-convert part
    const int r = bid - 24576;
    const int bx = (r & 63) * 32, by = (r >> 6) * 32;
    const int tx = t & 31, ty = t >> 5;    // 32 x 8
#pragma unroll
    for (int i = 0; i < 32; i += 8)
      ftile[ty + i][tx] = Wo[(long)(by + ty + i) * HID_DIM + bx + tx];
    __syncthreads();
#pragma unroll
    for (int i = 0; i < 32; i += 8)
      WoT[(long)(bx + ty + i) * HID_DIM + by + tx] = f2bf(ftile[tx][ty + i]);
  }
}

// ---- GEMM v9 (QKV): BM=256 x BN=128, wave tile 128x64 (MF=8) ----
// 3-slot ring, stage-2-ahead, counted vmcnt, 1 barrier/K-tile, setprio,
// T2 swizzle.  375 B LDS-read/MFMA.  72KB ring -> 2 blocks/CU.
// NOTE: (256,2) is REQUIRED — acc[8][4]+frags ~ 170 regs; (256,3) spills
// to scratch (round-16: 1.6GB scratch writes, 4x slowdown).
__global__ __launch_bounds__(256, 2) void gemm12(
    const unsigned short* __restrict__ A,
    const unsigned short* __restrict__ Bt0,
    unsigned short* __restrict__ Cb0,
    int M, int N, int K, long zsB, long zsC) {
  __shared__ __align__(16) unsigned short Abuf[3][256 * 32];  // 48KB
  __shared__ __align__(16) unsigned short Bbuf[3][128 * 32];  // 24KB
  const int t = threadIdx.x;         // 256
  const int lane = t & 63;
  const int w = t >> 6;              // 4 waves, 2M x 2N
  const int wr = w >> 1, wc = w & 1;
  const int l15 = lane & 15, l4 = lane >> 4;

  const int nwg = gridDim.x;
  const int bid = blockIdx.x;
  const int sw = (bid & 7) * (nwg >> 3) + (bid >> 3);
  const int nbx = N >> 7, nby = M >> 8;
  const int z = sw / (nbx * nby);
  const int rem = sw - z * nbx * nby;
  const int by = rem / nbx;
  const int bx = rem - by * nbx;

  const unsigned short* Bt = Bt0 + (long)z * zsB;
  unsigned short* Cb = Cb0 + (long)z * zsC;

  f32x4 acc[8][4] = {};

  const int kcol = 8 * ((t & 3) ^ ((t >> 3) & 3));
  const unsigned short* aSrc = A + ((long)by * 256 + (t >> 2)) * K + kcol;
  const unsigned short* bSrc = Bt + ((long)bx * 128 + (t >> 2)) * K + kcol;

  const int swzr = 8 * (l4 ^ ((l15 >> 1) & 3));
  const int aROff = (wr * 128 + l15) * 32 + swzr;   // + mi*512
  const int bROff = (wc * 64 + l15) * 32 + swzr;    // + ni*512

  const int NT = K >> 5;             // 32-wide K-tiles

#define STG(slot, kt_) do {                                              \
    _Pragma("unroll")                                                    \
    for (int r_ = 0; r_ < 4; ++r_)                                       \
      async_load16(aSrc + (long)(kt_) * 32 + (long)r_ * 64 * K,          \
                   (char*)(&Abuf[slot][0]) + r_ * 4096 + t * 16);        \
    _Pragma("unroll")                                                    \
    for (int r_ = 0; r_ < 2; ++r_)                                       \
      async_load16(bSrc + (long)(kt_) * 32 + (long)r_ * 64 * K,          \
                   (char*)(&Bbuf[slot][0]) + r_ * 4096 + t * 16);        \
  } while (0)

  STG(0, 0);
  STG(1, 1);
  asm volatile("s_waitcnt vmcnt(6)" ::: "memory");
  __builtin_amdgcn_s_barrier();

  int cur = 0;
  for (int kt = 0; kt < NT; ++kt) {
    const unsigned short* Ab = &Abuf[cur][0];
    const unsigned short* Bb = &Bbuf[cur][0];
    const bool stg = (kt + 2) < NT;
    u16x8 af[8], bfr[4];
#pragma unroll
    for (int n = 0; n < 4; ++n) bfr[n] = *(const u16x8*)&Bb[bROff + n * 512];
#pragma unroll
    for (int m = 0; m < 8; ++m) af[m] = *(const u16x8*)&Ab[aROff + m * 512];
    if (stg) {
      const int s2 = (cur + 2 >= 3) ? cur - 1 : cur + 2;
      STG(s2, kt + 2);
    }
    __builtin_amdgcn_s_setprio(1);
#pragma unroll
    for (int m = 0; m < 8; ++m)
#pragma unroll
      for (int n = 0; n < 4; ++n)
        acc[m][n] = mfma16(af[m], bfr[n], acc[m][n]);
    __builtin_amdgcn_s_setprio(0);
    __builtin_amdgcn_sched_barrier(0);
    if (kt + 1 < NT) {
      if (stg) asm volatile("s_waitcnt vmcnt(6)" ::: "memory");
      else     asm volatile("s_waitcnt vmcnt(0)" ::: "memory");
      __builtin_amdgcn_s_barrier();
    }
    cur = (cur + 1 >= 3) ? 0 : cur + 1;
  }
#undef STG

  const long orow = (long)by * 256 + wr * 128 + l4 * 4;
  const long ocol = (long)bx * 128 + wc * 64 + l15;
#pragma unroll
  for (int m = 0; m < 8; ++m)
#pragma unroll
    for (int n = 0; n < 4; ++n)
#pragma unroll
      for (int r = 0; r < 4; ++r)
        Cb[(orow + m * 16 + r) * N + ocol + n * 16] = f2bf(acc[m][n][r]);
}

// ---- GEMM v6 (Wo): BM=BN=128, 4 waves 64x64, 3 blocks/CU ----
__global__ __launch_bounds__(256, 3) void gemm10(
    const unsigned short* __restrict__ A,
    const unsigned short* __restrict__ Bt0,
    unsigned short* __restrict__ Cb0,
    float* __restrict__ Cf,
    int M, int N, int K, long zsB, long zsC) {
  __shared__ __align__(16) unsigned short Abuf[3][128 * 32];
  __shared__ __align__(16) unsigned short Bbuf[3][128 * 32];
  const int t = threadIdx.x;         // 256
  const int lane = t & 63;
  const int w = t >> 6;              // 4 waves, 2M x 2N
  const int wr = w >> 1, wc = w & 1;
  const int l15 = lane & 15, l4 = lane >> 4;

  const int nwg = gridDim.x;
  const int bid = blockIdx.x;
  const int sw = (bid & 7) * (nwg >> 3) + (bid >> 3);
  const int nbx = N >> 7, nby = M >> 7;
  const int z = sw / (nbx * nby);
  const int rem = sw - z * nbx * nby;
  const int by = rem / nbx;
  const int bx = rem - by * nbx;

  const unsigned short* Bt = Bt0 + (long)z * zsB;
  unsigned short* Cb = Cb0 ? Cb0 + (long)z * zsC : nullptr;

  f32x4 acc[4][4] = {};

  const int kcol = 8 * ((t & 3) ^ ((t >> 3) & 3));
  const unsigned short* aSrc = A + ((long)by * 128 + (t >> 2)) * K + kcol;
  const unsigned short* bSrc = Bt + ((long)bx * 128 + (t >> 2)) * K + kcol;

  const int swzr = 8 * (l4 ^ ((l15 >> 1) & 3));
  const int aROff = (wr * 64 + l15) * 32 + swzr;
  const int bROff = (wc * 64 + l15) * 32 + swzr;

  const int NT = K >> 5;             // 32-wide K-tiles

#define STG(slot, kt_) do {                                              \
    async_load16(aSrc + (long)(kt_) * 32,                                \
                 (char*)(&Abuf[slot][0]) + t * 16);                      \
    async_load16(aSrc + (long)(kt_) * 32 + 64L * K,                      \
                 (char*)(&Abuf[slot][0]) + 4096 + t * 16);               \
    async_load16(bSrc + (long)(kt_) * 32,                                \
                 (char*)(&Bbuf[slot][0]) + t * 16);                      \
    async_load16(bSrc + (long)(kt_) * 32 + 64L * K,                      \
                 (char*)(&Bbuf[slot][0]) + 4096 + t * 16);               \
  } while (0)

  STG(0, 0);
  STG(1, 1);
  asm volatile("s_waitcnt vmcnt(4)" ::: "memory");
  __builtin_amdgcn_s_barrier();

  int cur = 0;
  for (int kt = 0; kt < NT; ++kt) {
    const unsigned short* Ab = &Abuf[cur][0];
    const unsigned short* Bb = &Bbuf[cur][0];
    const bool stg = (kt + 2) < NT;
    u16x8 af[4], bfr[4];
#pragma unroll
    for (int n = 0; n < 4; ++n) bfr[n] = *(const u16x8*)&Bb[bROff + n * 512];
#pragma unroll
    for (int m = 0; m < 4; ++m) af[m] = *(const u16x8*)&Ab[aROff + m * 512];
    if (stg) {
      const int s2 = (cur + 2 >= 3) ? cur - 1 : cur + 2;
      STG(s2, kt + 2);
    }
    __builtin_amdgcn_s_setprio(1);
#pragma unroll
    for (int m = 0; m < 4; ++m)
#pragma unroll
      for (int n = 0; n < 4; ++n)
        acc[m][n] = mfma16(af[m], bfr[n], acc[m][n]);
    __builtin_amdgcn_s_setprio(0);
    __builtin_amdgcn_sched_barrier(0);
    if (kt + 1 < NT) {
      if (stg) asm volatile("s_waitcnt vmcnt(4)" ::: "memory");
      else     asm volatile("s_waitcnt vmcnt(0)" ::: "memory");
      __builtin_amdgcn_s_barrier();
    }
    cur = (cur + 1 >= 3) ? 0 : cur + 1;
  }
#undef STG

  const long orow = (long)by * 128 + wr * 64 + l4 * 4;
  const long ocol = (long)bx * 128 + wc * 64 + l15;
#pragma unroll
  for (int m = 0; m < 4; ++m)
#pragma unroll
    for (int n = 0; n < 4; ++n)
#pragma unroll
      for (int r = 0; r < 4; ++r) {
        const long row = orow + m * 16 + r;
        const long col = ocol + n * 16;
        if (Cb) Cb[row * N + col] = f2bf(acc[m][n][r]);
        else    Cf[row * N + col] = acc[m][n][r];
      }
}

// --------------- fused causal+alibi flash attention v9 -------------
// (round-11 champion, VGPR <= 128 verified)
__global__ __launch_bounds__(256, 4) void attn_fwd9(
    const unsigned short* __restrict__ Q,
    const unsigned short* __restrict__ K,
    const unsigned short* __restrict__ Vt,
    const float* __restrict__ alibi,
    unsigned short* __restrict__ O) {
  __shared__ __align__(16) unsigned short Kl[2][32 * 128];  // [k][d] swz
  __shared__ __align__(16) unsigned short Vl[2][64 * 64];   // [d>>1][(d&1),k] swz
  __shared__ __align__(16) unsigned short Pl[4][32][40];    // per-wave P
  const int t = threadIdx.x;
  const int lane = t & 63;
  const int w = t >> 6;
  const int l15 = lane & 15, l4 = lane >> 4;

  const int bid = blockIdx.x;                 // 512 blocks
  const int xcd = bid & 7;
  const int idx = bid >> 3;                   // 0..63
  const int qh = idx >> 4;                    // 0..3  (bh within xcd)
  const int ql = idx & 15;
  const int qt = (qh < 2) ? ql : (15 - ql);   // per-CU pairs sum to 15
  const int bh = xcd * 4 + qh;
  const int b = bh >> 4, h = bh & 15;
  const int q0b = qt * 128;
  const int q0 = q0b + w * 32;                 // wave's first q row
  const float nslope = alibi[h * S_LEN + 1];   // = -slope_h

  const long rowbase = ((long)b * S_LEN) * HID_DIM + h * HEAD_D; // Q,K,O
  const long vtbase  = ((long)bh * HEAD_D) * S_LEN;              // Vt

  u16x8 qf[2][4];
  {
    const unsigned short* qp = Q + rowbase + (long)(q0 + l15) * HID_DIM + l4 * 8;
#pragma unroll
    for (int m = 0; m < 2; ++m)
#pragma unroll
      for (int ds = 0; ds < 4; ++ds)
        qf[m][ds] = *(const u16x8*)(qp + (long)m * 16 * HID_DIM + ds * 32);
  }

  f32x4 acc[2][8] = {};
  float m_r[2] = {-1e30f, -1e30f};
  float l_r[2] = {0.f, 0.f};

  int dd, rw, cbl;
  dd = 16 * t;        rw = dd >> 8; cbl = (dd & 255) ^ ((rw & 7) << 4);
  const unsigned short* ksrc0 = K + rowbase + (long)rw * HID_DIM + (cbl >> 1);
  dd = 4096 + 16 * t; rw = dd >> 8; cbl = (dd & 255) ^ ((rw & 7) << 4);
  const unsigned short* ksrc1 = K + rowbase + (long)rw * HID_DIM + (cbl >> 1);
  dd = 16 * t;        rw = dd >> 7; cbl = (dd & 127) ^ ((rw & 3) << 4);
  const unsigned short* vsrc0 =
      Vt + vtbase + (long)(2 * rw + (cbl >> 6)) * S_LEN + ((cbl & 63) >> 1);
  dd = 4096 + 16 * t; rw = dd >> 7; cbl = (dd & 127) ^ ((rw & 3) << 4);
  const unsigned short* vsrc1 =
      Vt + vtbase + (long)(2 * rw + (cbl >> 6)) * S_LEN + ((cbl & 63) >> 1);

#define ASTAGE(buf, kt_) do {                                             \
    const long kadd = (long)(kt_) * 32 * HID_DIM;                         \
    async_load16(ksrc0 + kadd, (char*)(&Kl[buf][0]) + 16 * t);            \
    async_load16(ksrc1 + kadd, (char*)(&Kl[buf][0]) + 4096 + 16 * t);     \
    async_load16(vsrc0 + (kt_) * 32, (char*)(&Vl[buf][0]) + 16 * t);      \
    async_load16(vsrc1 + (kt_) * 32, (char*)(&Vl[buf][0]) + 4096 + 16 * t); \
  } while (0)

  const int ntB = qt * 4 + 4;            // block tile count
  const int mykt = q0 >> 5;              // wave's causal last tile

  ASTAGE(0, 0);
  __syncthreads();                       // drain vmcnt, tile 0 ready

  int cur = 0;
  for (int kt = 0; kt < ntB; ++kt) {
    const int kb = kt * 32;
    if (kt + 1 < ntB) ASTAGE(cur ^ 1, kt + 1);   // prefetch next tile
    if (kt <= mykt) {
      const char* Kc = (const char*)&Kl[cur][0];
      const char* Vc = (const char*)&Vl[cur][0];
      f32x4 sacc[2][2] = {};               // [n][m]
#pragma unroll
      for (int ds = 0; ds < 4; ++ds) {
        u16x8 kfr[2];
#pragma unroll
        for (int n = 0; n < 2; ++n) {
          const int R = 16 * n + l15;
          const int cb = (ds * 64 + l4 * 16) ^ ((l15 & 7) << 4);
          kfr[n] = *(const u16x8*)(Kc + R * 256 + cb);
        }
#pragma unroll
        for (int n = 0; n < 2; ++n)
#pragma unroll
          for (int m = 0; m < 2; ++m)
            sacc[n][m] = mfma16(kfr[n], qf[m][ds], sacc[n][m]);
      }
#pragma unroll
      for (int m = 0; m < 2; ++m) {
        const int q = q0 + 16 * m + l15;
        float pv[2][4];
        float rmax = -1e30f;
#pragma unroll
        for (int n = 0; n < 2; ++n)
#pragma unroll
          for (int r = 0; r < 4; ++r) {
            const int k = kb + 16 * n + l4 * 4 + r;
            float v = sacc[n][m][r] + nslope * (float)k;   // scale in Q
            if (k > q) v = -1e30f;
            pv[n][r] = v;
            rmax = fmaxf(rmax, v);
          }
        rmax = fmaxf(rmax, __shfl_xor(rmax, 16, 64));
        rmax = fmaxf(rmax, __shfl_xor(rmax, 32, 64));
        // T13 defer-max: only rescale when the max grew by > 8
        if (__ballot(rmax > m_r[m] + 8.f)) {
          const float mnew = fmaxf(m_r[m], rmax);
          const float sf = __expf(m_r[m] - mnew);
          m_r[m] = mnew;
          l_r[m] *= sf;
          float sfo[4];
#pragma unroll
          for (int r = 0; r < 4; ++r) sfo[r] = __shfl(sf, l4 * 4 + r, 64);
#pragma unroll
          for (int dt = 0; dt < 8; ++dt)
#pragma unroll
            for (int r = 0; r < 4; ++r) acc[m][dt][r] *= sfo[r];
        }
        float rsum = 0.f;
#pragma unroll
        for (int n = 0; n < 2; ++n)
#pragma unroll
          for (int r = 0; r < 4; ++r) {
            pv[n][r] = __expf(pv[n][r] - m_r[m]);   // bounded by e^8
            rsum += pv[n][r];
          }
        rsum += __shfl_xor(rsum, 16, 64);
        rsum += __shfl_xor(rsum, 32, 64);
        l_r[m] += rsum;
#pragma unroll
        for (int n = 0; n < 2; ++n) {
          u16x4 pk;
#pragma unroll
          for (int r = 0; r < 4; ++r) pk[r] = f2bf(pv[n][r]);
          *(u16x4*)&Pl[w][16 * m + l15][16 * n + l4 * 4] = pk;
        }
      }
      u16x8 pf[2];
#pragma unroll
      for (int m = 0; m < 2; ++m)
        pf[m] = *(const u16x8*)&Pl[w][16 * m + l15][l4 * 8];
#pragma unroll
      for (int dt = 0; dt < 8; ++dt) {
        const int d = dt * 16 + l15;
        const int vrow = d >> 1;
        const int cbv = (((d & 1) << 6) | (l4 << 4)) ^ ((vrow & 3) << 4);
        u16x8 vb = *(const u16x8*)(Vc + vrow * 128 + cbv);
#pragma unroll
        for (int m = 0; m < 2; ++m)
          acc[m][dt] = mfma16(pf[m], vb, acc[m][dt]);
      }
    }
    __builtin_amdgcn_sched_barrier(0);
    __syncthreads();                     // buf reads done + next tile landed
    cur ^= 1;
  }
#undef ASTAGE

#pragma unroll
  for (int m = 0; m < 2; ++m) {
    float linv[4];
#pragma unroll
    for (int r = 0; r < 4; ++r)
      linv[r] = 1.0f / __shfl(l_r[m], l4 * 4 + r, 64);
#pragma unroll
    for (int dt = 0; dt < 8; ++dt)
#pragma unroll
      for (int r = 0; r < 4; ++r) {
        const long row = q0 + 16 * m + l4 * 4 + r;
        O[rowbase + row * HID_DIM + dt * 16 + l15] = f2bf(acc[m][dt][r] * linv[r]);
      }
  }
}

extern "C" void kernel_launch(void* const* d_in, const int* in_sizes, int n_in,
                              void* d_out, int out_size, void* d_ws, size_t ws_size,
                              hipStream_t stream) {
  const float* x    = (const float*)d_in[0];
  const float* Wq   = (const float*)d_in[1];
  const float* Wk   = (const float*)d_in[2];
  const float* Wv   = (const float*)d_in[3];
  const float* Wo   = (const float*)d_in[4];
  // d_in[5] = attention_mask (causal, reproduced analytically)
  const float* alibi = (const float*)d_in[6];
  const float* fcos  = (const float*)d_in[7];
  const float* fsin  = (const float*)d_in[8];

  char* ws = (char*)d_ws;
  unsigned short* xb  = (unsigned short*)(ws);
  unsigned short* wtq = (unsigned short*)(ws + (16L << 20));
  unsigned short* wtk = (unsigned short*)(ws + (24L << 20));
  unsigned short* wtv = (unsigned short*)(ws + (32L << 20));
  unsigned short* VtG = (unsigned short*)(ws + (24L << 20));
  unsigned short* Qb  = (unsigned short*)(ws + (40L << 20));
  unsigned short* Kb  = (unsigned short*)(ws + (56L << 20));
  unsigned short* Vb  = (unsigned short*)(ws + (72L << 20));

  const int M = BATCH * S_LEN;   // 4096
  const int N = HID_DIM;         // 2048
  const int K = HID_DIM;         // 2048

  // fused prep: x cvt + Wq/Wk/Wv transposes (one dispatch)
  fused_prep<<<14336, 256, 0, stream>>>(x, xb, Wq, Wk, Wv, wtq, wtk, wtv);

  // fused QKV: 256x128 tiles, 3 z-panels -> 768 blocks (wave tile 128x64)
  gemm12<<<3 * (M / 256) * (N / 128), 256, 0, stream>>>(
      xb, wtq, Qb, M, N, K,
      (long)HID_DIM * HID_DIM, (long)(8 << 20));

  // fused mid: rope(Q,K) + V head-transpose + Wo transpose (one dispatch)
  // (Wo transpose reuses wtq, dead after gemm12; VtG overwrites wtk/wtv)
  fused_mid<<<28672, 256, 0, stream>>>(Qb, Kb, fcos, fsin, Vb, VtG, Wo, wtq);

  attn_fwd9<<<512, 256, 0, stream>>>(Qb, Kb, VtG, alibi, xb);

  // Wo GEMM: gemm10, 512 blocks, all co-resident
  gemm10<<<(M / 128) * (N / 128), 256, 0, stream>>>(
      xb, wtq, nullptr, (float*)d_out, M, N, K, 0L, 0L);
}